// Round 3
// baseline (3131.997 us; speedup 1.0000x reference)
//
#include <hip/hip_runtime.h>
#include <math.h>

#define KCODES 8192
#define DIM 256
#define HW 4096            // H*W
#define NROWS 32768        // B*H*W
#define DECAYF 0.99f
#define OMD 0.01f          // 1 - decay (f32(1.0-0.99) == 0.01f, verified)
#define EPSF 1e-5f

// ---------- K1a: inverse L2 norms of embedding rows ----------
__global__ __launch_bounds__(256) void k_rnorm(const float* __restrict__ emb,
                                               float* __restrict__ rnorm)
{
    int gw   = (blockIdx.x * 256 + threadIdx.x) >> 6;   // one wave per row
    int lane = threadIdx.x & 63;
    if (gw >= KCODES) return;
    float4 v = *(const float4*)(emb + (size_t)gw * DIM + lane * 4);
    float ss = v.x * v.x + v.y * v.y + v.z * v.z + v.w * v.w;
    #pragma unroll
    for (int m = 1; m < 64; m <<= 1) ss += __shfl_xor(ss, m, 64);
    if (lane == 0) rnorm[gw] = 1.0f / fmaxf(sqrtf(ss), 1e-12f);
}

// ---------- K1b: eT[d][k] = emb[k][d] * rnorm[k]  (LDS-tiled transpose) ----------
__global__ __launch_bounds__(256) void k_transpose(const float* __restrict__ emb,
                                                   const float* __restrict__ rnorm,
                                                   float* __restrict__ eT)
{
    __shared__ float tile[64][65];
    int kb = blockIdx.x >> 2;        // 0..127
    int db = blockIdx.x & 3;         // 0..3
    int k0 = kb * 64, d0 = db * 64;
    int lane = threadIdx.x & 63;
    int w    = threadIdx.x >> 6;
    #pragma unroll
    for (int it = 0; it < 16; ++it) {
        int row = it * 4 + w;
        tile[row][lane] = emb[(size_t)(k0 + row) * DIM + d0 + lane] * rnorm[k0 + row];
    }
    __syncthreads();
    #pragma unroll
    for (int it = 0; it < 16; ++it) {
        int drow = it * 4 + w;
        eT[(size_t)(d0 + drow) * KCODES + k0 + lane] = tile[lane][drow];
    }
}

// ---------- K1c: init EMA outputs with decay*old ----------
__global__ void k_init(const float* __restrict__ eavg, const float* __restrict__ cs,
                       float* __restrict__ oAvg, float* __restrict__ oCs)
{
    int t = blockIdx.x * 256 + threadIdx.x;
    if (t < KCODES * DIM) oAvg[t] = DECAYF * eavg[t];
    if (t < KCODES)       oCs[t]  = DECAYF * cs[t];
}

// ---------- K2: fused GEMM + argmax ----------
// block = 256 thr handles 64 rows of flat_z vs all K codes.
// zT[d][r] resident (64KB); eTile[d][c] streamed per 64-code chunk (64KB).
// 128KB LDS -> 1 block/CU (predicted occupancy bottleneck; measure first).
__global__ __launch_bounds__(256) void k_gemm_argmax(const float* __restrict__ z,
                                                     const float* __restrict__ eT,
                                                     int* __restrict__ idx)
{
    __shared__ float zT[DIM][64];
    __shared__ float eTile[DIM][64];
    int tid = threadIdx.x;
    int n0  = blockIdx.x * 64;           // 64 consecutive rows, same b (4096%64==0)
    int b   = n0 >> 12;
    int hw0 = n0 & 4095;
    const float* zb = z + (size_t)b * DIM * HW + hw0;

    int r = tid & 63;
    int w = tid >> 6;
    #pragma unroll 8
    for (int i = 0; i < 64; ++i) {
        int d = i * 4 + w;
        zT[d][r] = zb[(size_t)d * HW + r];   // coalesced read, conflict-free write
    }

    int tx = tid & 15, ty = tid >> 4;    // thread owns rows ty*4..+3, cols tx*4..+3 (per chunk)
    float best[4] = {-1e38f, -1e38f, -1e38f, -1e38f};
    int   bidx[4] = {0, 0, 0, 0};

    for (int k0 = 0; k0 < KCODES; k0 += 64) {
        __syncthreads();                 // also covers zT staging on first iter
        #pragma unroll
        for (int it = 0; it < 16; ++it) {
            int d = it * 16 + ty;
            *(float4*)&eTile[d][tx * 4] =
                *(const float4*)(eT + (size_t)d * KCODES + k0 + tx * 4);
        }
        __syncthreads();

        float acc[4][4];
        #pragma unroll
        for (int i = 0; i < 4; ++i)
            #pragma unroll
            for (int j = 0; j < 4; ++j) acc[i][j] = 0.0f;

        #pragma unroll 8
        for (int d = 0; d < DIM; ++d) {
            float4 a  = *(const float4*)&zT[d][ty * 4];
            float4 bb = *(const float4*)&eTile[d][tx * 4];
            float av[4] = {a.x, a.y, a.z, a.w};
            float bv[4] = {bb.x, bb.y, bb.z, bb.w};
            #pragma unroll
            for (int i = 0; i < 4; ++i)
                #pragma unroll
                for (int j = 0; j < 4; ++j)
                    acc[i][j] = fmaf(av[i], bv[j], acc[i][j]);
        }

        #pragma unroll
        for (int i = 0; i < 4; ++i)
            #pragma unroll
            for (int j = 0; j < 4; ++j) {
                float v = acc[i][j];
                if (v > best[i]) { best[i] = v; bidx[i] = k0 + tx * 4 + j; }
            }
    }

    // reduce across the 16 tx-lanes sharing each row; first-occurrence ties -> min idx
    #pragma unroll
    for (int i = 0; i < 4; ++i) {
        float v = best[i]; int ix = bidx[i];
        #pragma unroll
        for (int m = 1; m < 16; m <<= 1) {
            float ov = __shfl_xor(v, m, 64);
            int   oi = __shfl_xor(ix, m, 64);
            if (ov > v || (ov == v && oi < ix)) { v = ov; ix = oi; }
        }
        if (tx == 0) idx[n0 + ty * 4 + i] = ix;
    }
}

// ---------- K3a: counts + idx-as-float output ----------
__global__ void k_counts(const int* __restrict__ idx, float* __restrict__ oCs,
                         float* __restrict__ oIdx)
{
    int n = blockIdx.x * 256 + threadIdx.x;
    if (n >= NROWS) return;
    int k = idx[n];
    oIdx[n] = (float)k;
    atomicAdd(&oCs[k], OMD);
}

// ---------- K3b: embed_avg scatter-add (coalesced z reads) ----------
__global__ __launch_bounds__(256) void k_scatter(const float* __restrict__ z,
                                                 const int* __restrict__ idx,
                                                 float* __restrict__ oAvg)
{
    int tid = threadIdx.x;
    int n0  = blockIdx.x * 64;
    int b   = n0 >> 12, hw0 = n0 & 4095;
    const float* zb = z + (size_t)b * DIM * HW + hw0;
    int r = tid & 63, w = tid >> 6;
    int k = idx[n0 + r];
    float* dst = oAvg + (size_t)k * DIM;
    #pragma unroll 4
    for (int i = 0; i < 64; ++i) {
        int d = i * 4 + w;
        atomicAdd(&dst[d], OMD * zb[(size_t)d * HW + r]);
    }
}

// ---------- K4: z_q gather + straight-through output ----------
__global__ void k_zq(const float* __restrict__ z, const float* __restrict__ emb,
                     const int* __restrict__ idx,
                     float* __restrict__ oZqSt, float* __restrict__ oZq)
{
    int t  = blockIdx.x * 256 + threadIdx.x;  // < 8388608
    int hw = t & 4095;
    int d  = (t >> 12) & 255;
    int b  = t >> 20;
    int k  = idx[b * HW + hw];
    float e  = emb[(size_t)k * DIM + d];
    float zv = z[t];
    oZq[t]   = e;
    oZqSt[t] = zv + (e - zv);                 // literal STE arithmetic
}

// ---------- K5: n = sum(new_cluster_size), single block (deterministic) ----------
__global__ __launch_bounds__(256) void k_nsum(const float* __restrict__ oCs,
                                              float* __restrict__ nsum)
{
    __shared__ float red[256];
    float s = 0.0f;
    for (int t = threadIdx.x; t < KCODES; t += 256) s += oCs[t];
    red[threadIdx.x] = s;
    __syncthreads();
    for (int st = 128; st > 0; st >>= 1) {
        if (threadIdx.x < st) red[threadIdx.x] += red[threadIdx.x + st];
        __syncthreads();
    }
    if (threadIdx.x == 0) *nsum = red[0];
}

// ---------- K6: new_embedding = l2norm(new_embed_avg / cs) ----------
__global__ __launch_bounds__(256) void k_final_embed(const float* __restrict__ oAvg,
                                                     const float* __restrict__ oCs,
                                                     const float* __restrict__ nsum,
                                                     float* __restrict__ oEmb)
{
    int gw   = (blockIdx.x * 256 + threadIdx.x) >> 6;  // one wave per code
    int lane = threadIdx.x & 63;
    if (gw >= KCODES) return;
    float nt = *nsum;
    float cs = (oCs[gw] + EPSF) / (nt + (float)KCODES * EPSF) * nt;
    float4 v = *(const float4*)(oAvg + (size_t)gw * DIM + lane * 4);
    float t0 = v.x / cs, t1 = v.y / cs, t2 = v.z / cs, t3 = v.w / cs;
    float ss = t0 * t0 + t1 * t1 + t2 * t2 + t3 * t3;
    #pragma unroll
    for (int m = 1; m < 64; m <<= 1) ss += __shfl_xor(ss, m, 64);
    float scale = 1.0f / fmaxf(sqrtf(ss), 1e-12f);
    float4 o = {t0 * scale, t1 * scale, t2 * scale, t3 * scale};
    *(float4*)(oEmb + (size_t)gw * DIM + lane * 4) = o;
}

extern "C" void kernel_launch(void* const* d_in, const int* in_sizes, int n_in,
                              void* d_out, int out_size, void* d_ws, size_t ws_size,
                              hipStream_t stream)
{
    const float* z       = (const float*)d_in[0];
    const float* emb     = (const float*)d_in[1];
    const float* cluster = (const float*)d_in[2];
    const float* eavg    = (const float*)d_in[3];

    float* out   = (float*)d_out;
    float* oZqSt = out;                    // 8388608
    float* oIdx  = out + 8388608;          // 32768
    float* oZq   = out + 8421376;          // 8388608
    float* oEmb  = out + 16809984;         // 2097152
    float* oCs   = out + 18907136;         // 8192
    float* oAvg  = out + 18915328;         // 2097152

    float* ws    = (float*)d_ws;
    float* eT    = ws;                         // 2097152 floats (8 MB)
    float* rnorm = ws + 2097152;               // 8192
    int*   idx   = (int*)(ws + 2097152 + 8192);// 32768 ints
    float* nsum  = (float*)(idx + 32768);      // 1

    k_rnorm      <<<2048, 256, 0, stream>>>(emb, rnorm);
    k_transpose  <<<512, 256, 0, stream>>>(emb, rnorm, eT);
    k_init       <<<8192, 256, 0, stream>>>(eavg, cluster, oAvg, oCs);
    k_gemm_argmax<<<512, 256, 0, stream>>>(z, eT, idx);
    k_counts     <<<128, 256, 0, stream>>>(idx, oCs, oIdx);
    k_scatter    <<<512, 256, 0, stream>>>(z, idx, oAvg);
    k_zq         <<<32768, 256, 0, stream>>>(z, emb, idx, oZqSt, oZq);
    k_nsum       <<<1, 256, 0, stream>>>(oCs, nsum);
    k_final_embed<<<2048, 256, 0, stream>>>(oAvg, oCs, nsum, oEmb);
}

// Round 4
// 2536.863 us; speedup vs baseline: 1.2346x; 1.2346x over previous
//
#include <hip/hip_runtime.h>
#include <hip/hip_bf16.h>
#include <math.h>

#define KCODES 8192
#define DIM 256
#define HW 4096            // H*W
#define NROWS 32768        // B*H*W
#define DECAYF 0.99f
#define OMD 0.01f          // 1 - decay (f32(1.0-0.99) == 0.01f, verified)
#define EPSF 1e-5f
#define MARGIN 6e-4f       // 4x the rigorous approx-error bound (~1.5e-4)

typedef __attribute__((ext_vector_type(8))) short  short8;
typedef __attribute__((ext_vector_type(4))) float  f32x4;
typedef __attribute__((ext_vector_type(8))) unsigned short ushort8v;
typedef __attribute__((ext_vector_type(4))) unsigned short ushort4v;

// RNE float->bf16 (explicit, rounding-mode-certain for the error bound)
__device__ inline unsigned short f2bf_rne(float f) {
    unsigned u = __builtin_bit_cast(unsigned, f);
    u += 0x7fffu + ((u >> 16) & 1u);
    return (unsigned short)(u >> 16);
}
__device__ inline float bf2f(unsigned short u) {
    unsigned x = ((unsigned)u) << 16;
    return __builtin_bit_cast(float, x);
}

// XOR swizzle within a 32KB half-tile: 512B per code-row; spread 8 rows across 8 16B slots
#define SWZ(l) ((l) ^ ((((l) >> 9) & 7) << 4))

// ---------- K1a: inverse L2 norms of embedding rows (unchanged, round-3-proven) ----------
__global__ __launch_bounds__(256) void k_rnorm(const float* __restrict__ emb,
                                               float* __restrict__ rnorm)
{
    int gw   = (blockIdx.x * 256 + threadIdx.x) >> 6;
    int lane = threadIdx.x & 63;
    if (gw >= KCODES) return;
    float4 v = *(const float4*)(emb + (size_t)gw * DIM + lane * 4);
    float ss = v.x * v.x + v.y * v.y + v.z * v.z + v.w * v.w;
    #pragma unroll
    for (int m = 1; m < 64; m <<= 1) ss += __shfl_xor(ss, m, 64);
    if (lane == 0) rnorm[gw] = 1.0f / fmaxf(sqrtf(ss), 1e-12f);
}

// ---------- K1b: eT[d][k] fp32 (unchanged — feeds the exact fallback bit-identically) ----------
__global__ __launch_bounds__(256) void k_transpose(const float* __restrict__ emb,
                                                   const float* __restrict__ rnorm,
                                                   float* __restrict__ eT)
{
    __shared__ float tile[64][65];
    int kb = blockIdx.x >> 2;
    int db = blockIdx.x & 3;
    int k0 = kb * 64, d0 = db * 64;
    int lane = threadIdx.x & 63;
    int w    = threadIdx.x >> 6;
    #pragma unroll
    for (int it = 0; it < 16; ++it) {
        int row = it * 4 + w;
        tile[row][lane] = emb[(size_t)(k0 + row) * DIM + d0 + lane] * rnorm[k0 + row];
    }
    __syncthreads();
    #pragma unroll
    for (int it = 0; it < 16; ++it) {
        int drow = it * 4 + w;
        eT[(size_t)(d0 + drow) * KCODES + k0 + lane] = tile[lane][drow];
    }
}

// ---------- K1c: init EMA outputs (unchanged) ----------
__global__ void k_init(const float* __restrict__ eavg, const float* __restrict__ cs,
                       float* __restrict__ oAvg, float* __restrict__ oCs)
{
    int t = blockIdx.x * 256 + threadIdx.x;
    if (t < KCODES * DIM) oAvg[t] = DECAYF * eavg[t];
    if (t < KCODES)       oCs[t]  = DECAYF * cs[t];
}

// ---------- NEW: split z into bf16 hi/lo in row-major [n][d] (MFMA A layout) ----------
__global__ __launch_bounds__(256) void k_split_z(const float* __restrict__ z,
                                                 unsigned short* __restrict__ Ah,
                                                 unsigned short* __restrict__ Al)
{
    __shared__ float zT[DIM][64];
    const int tid = threadIdx.x;
    const int n0 = blockIdx.x * 64;
    const int b = n0 >> 12, hw0 = n0 & 4095;
    const float* zb = z + (size_t)b * DIM * HW + hw0;
    const int r = tid & 63, w = tid >> 6;
    #pragma unroll 8
    for (int i = 0; i < 64; ++i) {
        const int d = i * 4 + w;
        zT[d][r] = zb[(size_t)d * HW + r];        // coalesced
    }
    __syncthreads();
    const size_t ob = (size_t)(n0 + r) * DIM + w * 64;
    #pragma unroll
    for (int g = 0; g < 8; ++g) {
        ushort8v hu, lu;
        #pragma unroll
        for (int e = 0; e < 8; ++e) {
            const float f = zT[w * 64 + g * 8 + e][r];
            const unsigned short h = f2bf_rne(f);
            hu[e] = h;
            lu[e] = f2bf_rne(f - bf2f(h));        // residual is exact in fp32
        }
        *(ushort8v*)(Ah + ob + g * 8) = hu;
        *(ushort8v*)(Al + ob + g * 8) = lu;
    }
}

// ---------- NEW: split normalized codes into bf16 hi/lo, row-major [code][d] ----------
__global__ __launch_bounds__(256) void k_split_e(const float* __restrict__ emb,
                                                 const float* __restrict__ rnorm,
                                                 unsigned short* __restrict__ Bh,
                                                 unsigned short* __restrict__ Bl)
{
    const int gw = (blockIdx.x * 256 + threadIdx.x) >> 6;
    const int lane = threadIdx.x & 63;
    if (gw >= KCODES) return;
    const float sc = rnorm[gw];
    const float4 v = *(const float4*)(emb + (size_t)gw * DIM + lane * 4);
    float f[4] = {v.x * sc, v.y * sc, v.z * sc, v.w * sc};
    ushort4v hu, lu;
    #pragma unroll
    for (int e = 0; e < 4; ++e) {
        const unsigned short h = f2bf_rne(f[e]);
        hu[e] = h;
        lu[e] = f2bf_rne(f[e] - bf2f(h));
    }
    *(ushort4v*)(Bh + (size_t)gw * DIM + lane * 4) = hu;
    *(ushort4v*)(Bl + (size_t)gw * DIM + lane * 4) = lu;
}

// ---------- NEW K2: MFMA bf16-split GEMM + top-2 argmax + margin flag ----------
// 256 blocks x 128 rows. A (hi+lo) in registers; B double-buffered in LDS (128KB),
// staged via global_load_lds w=16 with inverse-swizzled source (T2/rule-21).
// T3-minimum 2-phase: stage(next) -> compute(cur) -> vmcnt(0)+barrier.
__global__ __launch_bounds__(256, 1) void k_gemm_bf16(
    const unsigned short* __restrict__ Ah, const unsigned short* __restrict__ Al,
    const unsigned short* __restrict__ Bh, const unsigned short* __restrict__ Bl,
    int* __restrict__ idx, int* __restrict__ flags)
{
    __shared__ unsigned short Blds[2][2][64 * 256];   // [buf][hi/lo][swizzled bytes/2]
    const int tid = threadIdx.x;
    const int w = tid >> 6, lane = tid & 63;
    const int l15 = lane & 15, kb = lane >> 4;
    const int n0 = blockIdx.x * 128;
    const int rowbase = n0 + w * 32;

    // ---- load A fragments once: [term][rowfrag][kstep], 16B per frag per lane ----
    short8 ah[2][8], al[2][8];
    #pragma unroll
    for (int rf = 0; rf < 2; ++rf) {
        const size_t rb = (size_t)(rowbase + rf * 16 + l15) * DIM + kb * 8;
        #pragma unroll
        for (int ks = 0; ks < 8; ++ks) {
            ah[rf][ks] = *(const short8*)(Ah + rb + ks * 32);
            al[rf][ks] = *(const short8*)(Al + rb + ks * 32);
        }
    }

    float b1v[8], b2v[8]; int b1i[8];
    #pragma unroll
    for (int s = 0; s < 8; ++s) { b1v[s] = -3e38f; b2v[s] = -3e38f; b1i[s] = 0; }

    // ---- staging: 32KB per term per chunk, linear LDS dest, swizzled global source ----
    auto stage = [&](int buf, int c) {
        const size_t gb = (size_t)c * (64 * 256);     // ushort offset of chunk
        #pragma unroll
        for (int i = 0; i < 8; ++i) {
            const int lbase = (i * 4 + w) * 1024;     // wave-uniform byte base in half-tile
            const int l = lbase + lane * 16;          // this lane's linear dest byte
            const int src = SWZ(l) >> 1;              // inverse-swizzled source (ushorts)
            __builtin_amdgcn_global_load_lds(
                (const __attribute__((address_space(1))) unsigned int*)(Bh + gb + src),
                (__attribute__((address_space(3))) unsigned int*)((char*)&Blds[buf][0][0] + lbase),
                16, 0, 0);
            __builtin_amdgcn_global_load_lds(
                (const __attribute__((address_space(1))) unsigned int*)(Bl + gb + src),
                (__attribute__((address_space(3))) unsigned int*)((char*)&Blds[buf][1][0] + lbase),
                16, 0, 0);
        }
    };

    stage(0, 0);
    asm volatile("s_waitcnt vmcnt(0)" ::: "memory");
    __builtin_amdgcn_s_barrier();

    for (int c = 0; c < 128; ++c) {
        const int buf = c & 1;
        if (c < 127) stage(buf ^ 1, c + 1);           // issue early, lands under compute

        f32x4 acc[2][4];
        #pragma unroll
        for (int rf = 0; rf < 2; ++rf)
            #pragma unroll
            for (int cf = 0; cf < 4; ++cf)
                acc[rf][cf] = (f32x4){0.f, 0.f, 0.f, 0.f};

        #pragma unroll
        for (int ks = 0; ks < 8; ++ks) {
            short8 bh[4], bl[4];
            #pragma unroll
            for (int cf = 0; cf < 4; ++cf) {
                const int col = cf * 16 + l15;
                int byte = col * 512 + ks * 64 + kb * 16;
                byte ^= (col & 7) << 4;               // T2 read-side swizzle
                bh[cf] = *(const short8*)((const char*)&Blds[buf][0][0] + byte);
                bl[cf] = *(const short8*)((const char*)&Blds[buf][1][0] + byte);
            }
            // term-major order: same-acc dependency spacing = 8 MFMAs
            #pragma unroll
            for (int rf = 0; rf < 2; ++rf)
                #pragma unroll
                for (int cf = 0; cf < 4; ++cf)
                    acc[rf][cf] = __builtin_amdgcn_mfma_f32_16x16x32_bf16(ah[rf][ks], bh[cf], acc[rf][cf], 0, 0, 0);
            #pragma unroll
            for (int rf = 0; rf < 2; ++rf)
                #pragma unroll
                for (int cf = 0; cf < 4; ++cf)
                    acc[rf][cf] = __builtin_amdgcn_mfma_f32_16x16x32_bf16(ah[rf][ks], bl[cf], acc[rf][cf], 0, 0, 0);
            #pragma unroll
            for (int rf = 0; rf < 2; ++rf)
                #pragma unroll
                for (int cf = 0; cf < 4; ++cf)
                    acc[rf][cf] = __builtin_amdgcn_mfma_f32_16x16x32_bf16(al[rf][ks], bh[cf], acc[rf][cf], 0, 0, 0);
            #pragma unroll
            for (int rf = 0; rf < 2; ++rf)
                #pragma unroll
                for (int cf = 0; cf < 4; ++cf)
                    acc[rf][cf] = __builtin_amdgcn_mfma_f32_16x16x32_bf16(al[rf][ks], bl[cf], acc[rf][cf], 0, 0, 0);
        }

        // top-2 update (overlaps with in-flight stage)
        const int colb = c * 64 + l15;
        #pragma unroll
        for (int rf = 0; rf < 2; ++rf)
            #pragma unroll
            for (int cf = 0; cf < 4; ++cf)
                #pragma unroll
                for (int q = 0; q < 4; ++q) {
                    const float v = acc[rf][cf][q];
                    const int s = rf * 4 + q;
                    const int col = colb + cf * 16;
                    if (v > b1v[s]) { b2v[s] = b1v[s]; b1v[s] = v; b1i[s] = col; }
                    else if (v > b2v[s]) b2v[s] = v;
                }

        asm volatile("s_waitcnt vmcnt(0)" ::: "memory");
        __builtin_amdgcn_s_barrier();
    }

    // cross-lane top-2 merge within each 16-lane group; tie -> min idx (np.argmax)
    #pragma unroll
    for (int s = 0; s < 8; ++s) {
        float v1 = b1v[s], v2 = b2v[s]; int i1 = b1i[s];
        #pragma unroll
        for (int m = 1; m < 16; m <<= 1) {
            const float o1 = __shfl_xor(v1, m, 64);
            const int   oi = __shfl_xor(i1, m, 64);
            const float o2 = __shfl_xor(v2, m, 64);
            const float lo = fminf(v1, o1);
            v2 = fmaxf(fmaxf(v2, o2), lo);
            const bool take = (o1 > v1) || (o1 == v1 && oi < i1);
            v1 = take ? o1 : v1;
            i1 = take ? oi : i1;
        }
        if (l15 == 0) {
            const int rf = s >> 2, q = s & 3;
            const int row = rowbase + rf * 16 + kb * 4 + q;
            idx[row]   = i1;
            flags[row] = (v1 - v2 < MARGIN) ? 1 : 0;
        }
    }
}

// ---------- NEW: exact fp32 fallback for flagged rows (replays round-3 arithmetic) ----------
__global__ __launch_bounds__(256) void k_exact(const float* __restrict__ z,
                                               const float* __restrict__ eT,
                                               const int* __restrict__ flags,
                                               int* __restrict__ idx)
{
    __shared__ float zrow[DIM];
    __shared__ float rv[256];
    __shared__ int   ri[256];
    const int tid = threadIdx.x;
    const int n0 = blockIdx.x * 64;
    const unsigned long long m = __ballot(flags[n0 + (tid & 63)] != 0);
    if (m == 0) return;
    for (int r = 0; r < 64; ++r) {
        if (!((m >> r) & 1ull)) continue;
        const int n = n0 + r;
        const int b = n >> 12, hw = n & 4095;
        __syncthreads();
        if (tid < DIM) zrow[tid] = z[(size_t)b * DIM * HW + (size_t)tid * HW + hw];
        __syncthreads();
        float bv = -3e38f; int bi = 0;
        for (int j = 0; j < 32; ++j) {
            const int cc = j * 256 + tid;
            float s = 0.f;
            #pragma unroll 8
            for (int d = 0; d < DIM; ++d)
                s = fmaf(zrow[d], eT[(size_t)d * KCODES + cc], s);  // bit-identical to round-3 chain
            if (s > bv) { bv = s; bi = cc; }                        // ascending cc -> first occurrence
        }
        rv[tid] = bv; ri[tid] = bi;
        __syncthreads();
        for (int st = 128; st > 0; st >>= 1) {
            if (tid < st) {
                const float ov = rv[tid + st]; const int oi = ri[tid + st];
                if (ov > rv[tid] || (ov == rv[tid] && oi < ri[tid])) { rv[tid] = ov; ri[tid] = oi; }
            }
            __syncthreads();
        }
        if (tid == 0) idx[n] = ri[0];
    }
}

// ---------- K3a: counts + idx-as-float output (unchanged) ----------
__global__ void k_counts(const int* __restrict__ idx, float* __restrict__ oCs,
                         float* __restrict__ oIdx)
{
    int n = blockIdx.x * 256 + threadIdx.x;
    if (n >= NROWS) return;
    int k = idx[n];
    oIdx[n] = (float)k;
    atomicAdd(&oCs[k], OMD);
}

// ---------- K3b: embed_avg scatter-add (unchanged) ----------
__global__ __launch_bounds__(256) void k_scatter(const float* __restrict__ z,
                                                 const int* __restrict__ idx,
                                                 float* __restrict__ oAvg)
{
    int tid = threadIdx.x;
    int n0  = blockIdx.x * 64;
    int b   = n0 >> 12, hw0 = n0 & 4095;
    const float* zb = z + (size_t)b * DIM * HW + hw0;
    int r = tid & 63, w = tid >> 6;
    int k = idx[n0 + r];
    float* dst = oAvg + (size_t)k * DIM;
    #pragma unroll 4
    for (int i = 0; i < 64; ++i) {
        int d = i * 4 + w;
        atomicAdd(&dst[d], OMD * zb[(size_t)d * HW + r]);
    }
}

// ---------- K4: z_q gather + straight-through (unchanged; runs AFTER scratch use) ----------
__global__ void k_zq(const float* __restrict__ z, const float* __restrict__ emb,
                     const int* __restrict__ idx,
                     float* __restrict__ oZqSt, float* __restrict__ oZq)
{
    int t  = blockIdx.x * 256 + threadIdx.x;
    int hw = t & 4095;
    int d  = (t >> 12) & 255;
    int b  = t >> 20;
    int k  = idx[b * HW + hw];
    float e  = emb[(size_t)k * DIM + d];
    float zv = z[t];
    oZq[t]   = e;
    oZqSt[t] = zv + (e - zv);
}

// ---------- K5: n = sum(new_cluster_size) (unchanged) ----------
__global__ __launch_bounds__(256) void k_nsum(const float* __restrict__ oCs,
                                              float* __restrict__ nsum)
{
    __shared__ float red[256];
    float s = 0.0f;
    for (int t = threadIdx.x; t < KCODES; t += 256) s += oCs[t];
    red[threadIdx.x] = s;
    __syncthreads();
    for (int st = 128; st > 0; st >>= 1) {
        if (threadIdx.x < st) red[threadIdx.x] += red[threadIdx.x + st];
        __syncthreads();
    }
    if (threadIdx.x == 0) *nsum = red[0];
}

// ---------- K6: new_embedding = l2norm(new_embed_avg / cs) (unchanged) ----------
__global__ __launch_bounds__(256) void k_final_embed(const float* __restrict__ oAvg,
                                                     const float* __restrict__ oCs,
                                                     const float* __restrict__ nsum,
                                                     float* __restrict__ oEmb)
{
    int gw   = (blockIdx.x * 256 + threadIdx.x) >> 6;
    int lane = threadIdx.x & 63;
    if (gw >= KCODES) return;
    float nt = *nsum;
    float cs = (oCs[gw] + EPSF) / (nt + (float)KCODES * EPSF) * nt;
    float4 v = *(const float4*)(oAvg + (size_t)gw * DIM + lane * 4);
    float t0 = v.x / cs, t1 = v.y / cs, t2 = v.z / cs, t3 = v.w / cs;
    float ss = t0 * t0 + t1 * t1 + t2 * t2 + t3 * t3;
    #pragma unroll
    for (int m = 1; m < 64; m <<= 1) ss += __shfl_xor(ss, m, 64);
    float scale = 1.0f / fmaxf(sqrtf(ss), 1e-12f);
    float4 o = {t0 * scale, t1 * scale, t2 * scale, t3 * scale};
    *(float4*)(oEmb + (size_t)gw * DIM + lane * 4) = o;
}

extern "C" void kernel_launch(void* const* d_in, const int* in_sizes, int n_in,
                              void* d_out, int out_size, void* d_ws, size_t ws_size,
                              hipStream_t stream)
{
    const float* z       = (const float*)d_in[0];
    const float* emb     = (const float*)d_in[1];
    const float* cluster = (const float*)d_in[2];
    const float* eavg    = (const float*)d_in[3];

    float* out   = (float*)d_out;
    float* oZqSt = out;                    // 8388608
    float* oIdx  = out + 8388608;          // 32768
    float* oZq   = out + 8421376;          // 8388608
    float* oEmb  = out + 16809984;         // 2097152
    float* oCs   = out + 18907136;         // 8192
    float* oAvg  = out + 18915328;         // 2097152

    // bf16 operand scratch lives in out-regions written only at the very end:
    //   Ah/Al occupy the oZqSt region (33.55 MB exactly); Bh/Bl the head of oZq.
    unsigned short* Ah = (unsigned short*)oZqSt;            // 8388608 ushorts
    unsigned short* Al = Ah + 8388608;                      // 8388608 ushorts
    unsigned short* Bh = (unsigned short*)oZq;              // 2097152 ushorts
    unsigned short* Bl = Bh + 2097152;                      // 2097152 ushorts

    float* ws    = (float*)d_ws;
    float* eT    = ws;                              // 2097152 floats (8 MB)
    float* rnorm = ws + 2097152;                    // 8192
    int*   idx   = (int*)(ws + 2097152 + 8192);     // 32768 ints
    float* nsum  = (float*)(idx + 32768);           // 1
    int*   flags = (int*)(nsum + 1);                // 32768 ints

    k_rnorm      <<<2048, 256, 0, stream>>>(emb, rnorm);
    k_transpose  <<<512, 256, 0, stream>>>(emb, rnorm, eT);       // for exact fallback
    k_split_e    <<<2048, 256, 0, stream>>>(emb, rnorm, Bh, Bl);
    k_split_z    <<<512, 256, 0, stream>>>(z, Ah, Al);
    k_init       <<<8192, 256, 0, stream>>>(eavg, cluster, oAvg, oCs);
    k_gemm_bf16  <<<256, 256, 0, stream>>>(Ah, Al, Bh, Bl, idx, flags);
    k_exact      <<<512, 256, 0, stream>>>(z, eT, flags, idx);
    k_counts     <<<128, 256, 0, stream>>>(idx, oCs, oIdx);
    k_scatter    <<<512, 256, 0, stream>>>(z, idx, oAvg);
    k_zq         <<<32768, 256, 0, stream>>>(z, emb, idx, oZqSt, oZq);
    k_nsum       <<<1, 256, 0, stream>>>(oCs, nsum);
    k_final_embed<<<2048, 256, 0, stream>>>(oAvg, oCs, nsum, oEmb);
}

// Round 5
// 1487.917 us; speedup vs baseline: 2.1050x; 1.7050x over previous
//
#include <hip/hip_runtime.h>
#include <hip/hip_bf16.h>
#include <math.h>

#define KCODES 8192
#define DIM 256
#define HW 4096            // H*W
#define NROWS 32768        // B*H*W
#define DECAYF 0.99f
#define OMD 0.01f          // 1 - decay (f32(1.0-0.99) == 0.01f, verified)
#define EPSF 1e-5f
#define MARGIN 1e-3f       // covers 2x(split residual + dropped lo*lo + accum rounding), worst-case

typedef __attribute__((ext_vector_type(8))) short  short8;
typedef __attribute__((ext_vector_type(4))) float  f32x4;
typedef __attribute__((ext_vector_type(8))) unsigned short ushort8v;
typedef __attribute__((ext_vector_type(4))) unsigned short ushort4v;

// RNE float->bf16 (explicit, rounding-mode-certain for the error bound)
__device__ inline unsigned short f2bf_rne(float f) {
    unsigned u = __builtin_bit_cast(unsigned, f);
    u += 0x7fffu + ((u >> 16) & 1u);
    return (unsigned short)(u >> 16);
}
__device__ inline float bf2f(unsigned short u) {
    unsigned x = ((unsigned)u) << 16;
    return __builtin_bit_cast(float, x);
}

// XOR swizzle within a 32KB half-tile (round-4-proven involution, rule #21)
#define SWZ(l) ((l) ^ ((((l) >> 9) & 7) << 4))

// ---------- K1a: inverse L2 norms of embedding rows ----------
__global__ __launch_bounds__(256) void k_rnorm(const float* __restrict__ emb,
                                               float* __restrict__ rnorm)
{
    int gw   = (blockIdx.x * 256 + threadIdx.x) >> 6;
    int lane = threadIdx.x & 63;
    if (gw >= KCODES) return;
    float4 v = *(const float4*)(emb + (size_t)gw * DIM + lane * 4);
    float ss = v.x * v.x + v.y * v.y + v.z * v.z + v.w * v.w;
    #pragma unroll
    for (int m = 1; m < 64; m <<= 1) ss += __shfl_xor(ss, m, 64);
    if (lane == 0) rnorm[gw] = 1.0f / fmaxf(sqrtf(ss), 1e-12f);
}

// ---------- K1b: eT[d][k] fp32 (feeds the exact fallback bit-identically) ----------
__global__ __launch_bounds__(256) void k_transpose(const float* __restrict__ emb,
                                                   const float* __restrict__ rnorm,
                                                   float* __restrict__ eT)
{
    __shared__ float tile[64][65];
    int kb = blockIdx.x >> 2;
    int db = blockIdx.x & 3;
    int k0 = kb * 64, d0 = db * 64;
    int lane = threadIdx.x & 63;
    int w    = threadIdx.x >> 6;
    #pragma unroll
    for (int it = 0; it < 16; ++it) {
        int row = it * 4 + w;
        tile[row][lane] = emb[(size_t)(k0 + row) * DIM + d0 + lane] * rnorm[k0 + row];
    }
    __syncthreads();
    #pragma unroll
    for (int it = 0; it < 16; ++it) {
        int drow = it * 4 + w;
        eT[(size_t)(d0 + drow) * KCODES + k0 + lane] = tile[lane][drow];
    }
}

// ---------- K1c: init EMA outputs + zero the flag counter ----------
__global__ void k_init(const float* __restrict__ eavg, const float* __restrict__ cs,
                       float* __restrict__ oAvg, float* __restrict__ oCs,
                       int* __restrict__ count)
{
    int t = blockIdx.x * 256 + threadIdx.x;
    if (t == 0 && blockIdx.x == 0) *count = 0;
    if (t < KCODES * DIM) oAvg[t] = DECAYF * eavg[t];
    if (t < KCODES)       oCs[t]  = DECAYF * cs[t];
}

// ---------- split z into bf16 hi/lo in row-major [n][d] (MFMA A layout) ----------
__global__ __launch_bounds__(256) void k_split_z(const float* __restrict__ z,
                                                 unsigned short* __restrict__ Ah,
                                                 unsigned short* __restrict__ Al)
{
    __shared__ float zT[DIM][64];
    const int tid = threadIdx.x;
    const int n0 = blockIdx.x * 64;
    const int b = n0 >> 12, hw0 = n0 & 4095;
    const float* zb = z + (size_t)b * DIM * HW + hw0;
    const int r = tid & 63, w = tid >> 6;
    #pragma unroll 8
    for (int i = 0; i < 64; ++i) {
        const int d = i * 4 + w;
        zT[d][r] = zb[(size_t)d * HW + r];
    }
    __syncthreads();
    const size_t ob = (size_t)(n0 + r) * DIM + w * 64;
    #pragma unroll
    for (int g = 0; g < 8; ++g) {
        ushort8v hu, lu;
        #pragma unroll
        for (int e = 0; e < 8; ++e) {
            const float f = zT[w * 64 + g * 8 + e][r];
            const unsigned short h = f2bf_rne(f);
            hu[e] = h;
            lu[e] = f2bf_rne(f - bf2f(h));
        }
        *(ushort8v*)(Ah + ob + g * 8) = hu;
        *(ushort8v*)(Al + ob + g * 8) = lu;
    }
}

// ---------- split normalized codes into bf16 hi/lo, row-major [code][d] ----------
__global__ __launch_bounds__(256) void k_split_e(const float* __restrict__ emb,
                                                 const float* __restrict__ rnorm,
                                                 unsigned short* __restrict__ Bh,
                                                 unsigned short* __restrict__ Bl)
{
    const int gw = (blockIdx.x * 256 + threadIdx.x) >> 6;
    const int lane = threadIdx.x & 63;
    if (gw >= KCODES) return;
    const float sc = rnorm[gw];
    const float4 v = *(const float4*)(emb + (size_t)gw * DIM + lane * 4);
    float f[4] = {v.x * sc, v.y * sc, v.z * sc, v.w * sc};
    ushort4v hu, lu;
    #pragma unroll
    for (int e = 0; e < 4; ++e) {
        const unsigned short h = f2bf_rne(f[e]);
        hu[e] = h;
        lu[e] = f2bf_rne(f[e] - bf2f(h));
    }
    *(ushort4v*)(Bh + (size_t)gw * DIM + lane * 4) = hu;
    *(ushort4v*)(Bl + (size_t)gw * DIM + lane * 4) = lu;
}

// ---------- K2: MFMA bf16-split GEMM (3 terms) + top-2 argmax + margin flag ----------
// Counted-vmcnt double buffer (T4): stage(c+1) issued BEFORE waiting, wait vmcnt(16)
// so stage(c+1)'s 16 loads stay in flight across the barrier.
__global__ __launch_bounds__(256, 1) void k_gemm_bf16(
    const unsigned short* __restrict__ Ah, const unsigned short* __restrict__ Al,
    const unsigned short* __restrict__ Bh, const unsigned short* __restrict__ Bl,
    int* __restrict__ idx, int* __restrict__ flags)
{
    __shared__ unsigned short Blds[2][2][64 * 256];   // [buf][hi/lo][swizzled]
    const int tid = threadIdx.x;
    const int w = tid >> 6, lane = tid & 63;
    const int l15 = lane & 15, kb = lane >> 4;
    const int n0 = blockIdx.x * 128;
    const int rowbase = n0 + w * 32;

    // ---- load A fragments once ----
    short8 ah[2][8], al[2][8];
    #pragma unroll
    for (int rf = 0; rf < 2; ++rf) {
        const size_t rb = (size_t)(rowbase + rf * 16 + l15) * DIM + kb * 8;
        #pragma unroll
        for (int ks = 0; ks < 8; ++ks) {
            ah[rf][ks] = *(const short8*)(Ah + rb + ks * 32);
            al[rf][ks] = *(const short8*)(Al + rb + ks * 32);
        }
    }

    float b1v[8], b2v[8]; int b1i[8];
    #pragma unroll
    for (int s = 0; s < 8; ++s) { b1v[s] = -3e38f; b2v[s] = -3e38f; b1i[s] = 0; }

    auto stage = [&](int buf, int c) {   // 16 global_load_lds per wave
        const size_t gb = (size_t)c * (64 * 256);
        #pragma unroll
        for (int i = 0; i < 8; ++i) {
            const int lbase = (i * 4 + w) * 1024;
            const int l = lbase + lane * 16;
            const int src = SWZ(l) >> 1;
            __builtin_amdgcn_global_load_lds(
                (const __attribute__((address_space(1))) unsigned int*)(Bh + gb + src),
                (__attribute__((address_space(3))) unsigned int*)((char*)&Blds[buf][0][0] + lbase),
                16, 0, 0);
            __builtin_amdgcn_global_load_lds(
                (const __attribute__((address_space(1))) unsigned int*)(Bl + gb + src),
                (__attribute__((address_space(3))) unsigned int*)((char*)&Blds[buf][1][0] + lbase),
                16, 0, 0);
        }
    };

    stage(0, 0);

    for (int c = 0; c < 128; ++c) {
        const int buf = c & 1;
        if (c < 127) {
            stage(buf ^ 1, c + 1);                    // issue early: stays in flight
            asm volatile("s_waitcnt vmcnt(16)" ::: "memory");   // stage(c) landed
        } else {
            asm volatile("s_waitcnt vmcnt(0)" ::: "memory");
        }
        __builtin_amdgcn_sched_barrier(0);
        __builtin_amdgcn_s_barrier();

        f32x4 acc[2][4];
        #pragma unroll
        for (int rf = 0; rf < 2; ++rf)
            #pragma unroll
            for (int cf = 0; cf < 4; ++cf)
                acc[rf][cf] = (f32x4){0.f, 0.f, 0.f, 0.f};

        #pragma unroll
        for (int ks = 0; ks < 8; ++ks) {
            short8 bh[4], bl[4];
            #pragma unroll
            for (int cf = 0; cf < 4; ++cf) {
                const int col = cf * 16 + l15;
                int byte = col * 512 + ks * 64 + kb * 16;
                byte ^= (col & 7) << 4;               // read-side swizzle (involution)
                bh[cf] = *(const short8*)((const char*)&Blds[buf][0][0] + byte);
                bl[cf] = *(const short8*)((const char*)&Blds[buf][1][0] + byte);
            }
            // 3 terms: hh, hl, lh (ll dropped; bound 2^-18*||z|| covered by MARGIN)
            #pragma unroll
            for (int rf = 0; rf < 2; ++rf)
                #pragma unroll
                for (int cf = 0; cf < 4; ++cf)
                    acc[rf][cf] = __builtin_amdgcn_mfma_f32_16x16x32_bf16(ah[rf][ks], bh[cf], acc[rf][cf], 0, 0, 0);
            #pragma unroll
            for (int rf = 0; rf < 2; ++rf)
                #pragma unroll
                for (int cf = 0; cf < 4; ++cf)
                    acc[rf][cf] = __builtin_amdgcn_mfma_f32_16x16x32_bf16(ah[rf][ks], bl[cf], acc[rf][cf], 0, 0, 0);
            #pragma unroll
            for (int rf = 0; rf < 2; ++rf)
                #pragma unroll
                for (int cf = 0; cf < 4; ++cf)
                    acc[rf][cf] = __builtin_amdgcn_mfma_f32_16x16x32_bf16(al[rf][ks], bh[cf], acc[rf][cf], 0, 0, 0);
        }

        const int colb = c * 64 + l15;
        #pragma unroll
        for (int rf = 0; rf < 2; ++rf)
            #pragma unroll
            for (int cf = 0; cf < 4; ++cf)
                #pragma unroll
                for (int q = 0; q < 4; ++q) {
                    const float v = acc[rf][cf][q];
                    const int s = rf * 4 + q;
                    const int col = colb + cf * 16;
                    if (v > b1v[s]) { b2v[s] = b1v[s]; b1v[s] = v; b1i[s] = col; }
                    else if (v > b2v[s]) b2v[s] = v;
                }

        __builtin_amdgcn_s_barrier();                 // all reads of buf done
    }

    // cross-lane top-2 merge; tie -> min idx (np.argmax first-occurrence)
    #pragma unroll
    for (int s = 0; s < 8; ++s) {
        float v1 = b1v[s], v2 = b2v[s]; int i1 = b1i[s];
        #pragma unroll
        for (int m = 1; m < 16; m <<= 1) {
            const float o1 = __shfl_xor(v1, m, 64);
            const int   oi = __shfl_xor(i1, m, 64);
            const float o2 = __shfl_xor(v2, m, 64);
            const float lo = fminf(v1, o1);
            v2 = fmaxf(fmaxf(v2, o2), lo);
            const bool take = (o1 > v1) || (o1 == v1 && oi < i1);
            v1 = take ? o1 : v1;
            i1 = take ? oi : i1;
        }
        if (l15 == 0) {
            const int rf = s >> 2, q = s & 3;
            const int row = rowbase + rf * 16 + kb * 4 + q;
            idx[row]   = i1;
            flags[row] = (v1 - v2 < MARGIN) ? 1 : 0;
        }
    }
}

// ---------- compact flagged rows ----------
__global__ void k_flagscan(const int* __restrict__ flags, int* __restrict__ list,
                           int* __restrict__ count)
{
    int n = blockIdx.x * 256 + threadIdx.x;
    if (n < NROWS && flags[n]) {
        int p = atomicAdd(count, 1);
        list[p] = n;
    }
}

// ---------- batched exact recheck: job = (16-row group) x (1024-code chunk) ----------
// Chain per (row,code) is bit-identical to the round-3-proven fp32 fmaf chain.
__global__ __launch_bounds__(256) void k_exact2(const float* __restrict__ z,
                                                const float* __restrict__ eT,
                                                const int* __restrict__ list,
                                                const int* __restrict__ count,
                                                float* __restrict__ pv,
                                                int* __restrict__ pi)
{
    __shared__ float zl[16][256];
    __shared__ float sv[256];
    __shared__ int   si[256];
    const int cnt = *count;
    const int totalJobs = ((cnt + 15) >> 4) << 3;     // groups * 8 chunks
    const int t = threadIdx.x;

    for (int j = blockIdx.x; j < totalJobs; j += gridDim.x) {
        const int slot = j >> 3, kc = j & 7;
        __syncthreads();
        #pragma unroll
        for (int i = 0; i < 16; ++i) {
            const int s = slot * 16 + i;
            const int n = (s < cnt) ? list[s] : list[0];
            const int b = n >> 12, hw = n & 4095;
            zl[i][t] = z[(size_t)b * DIM * HW + (size_t)t * HW + hw];   // d = t
        }
        __syncthreads();

        float acc[16][4];
        #pragma unroll
        for (int i = 0; i < 16; ++i)
            #pragma unroll
            for (int q = 0; q < 4; ++q) acc[i][q] = 0.f;

        const float* eb = eT + kc * 1024 + t;
        #pragma unroll 2
        for (int d = 0; d < DIM; ++d) {
            float ev[4];
            #pragma unroll
            for (int q = 0; q < 4; ++q) ev[q] = eb[(size_t)d * KCODES + q * 256];
            #pragma unroll
            for (int i = 0; i < 16; ++i) {
                const float zv = zl[i][d];
                #pragma unroll
                for (int q = 0; q < 4; ++q)
                    acc[i][q] = fmaf(zv, ev[q], acc[i][q]);
            }
        }

        // per-row block reduction (tie -> min idx)
        for (int i = 0; i < 16; ++i) {
            float bv = -3e38f; int bi = 0x7fffffff;
            #pragma unroll
            for (int q = 0; q < 4; ++q) {
                const int code = kc * 1024 + t + q * 256;
                const float v = acc[i][q];
                if (v > bv || (v == bv && code < bi)) { bv = v; bi = code; }
            }
            __syncthreads();
            sv[t] = bv; si[t] = bi;
            __syncthreads();
            for (int st = 128; st > 0; st >>= 1) {
                if (t < st) {
                    const float ov = sv[t + st]; const int oi = si[t + st];
                    if (ov > sv[t] || (ov == sv[t] && oi < si[t])) { sv[t] = ov; si[t] = oi; }
                }
                __syncthreads();
            }
            const int s = slot * 16 + i;
            if (t == 0 && s < cnt) {
                pv[s * 8 + kc] = sv[0];
                pi[s * 8 + kc] = si[0];
            }
        }
    }
}

// ---------- merge 8 chunk-partials per flagged row ----------
__global__ void k_merge(const int* __restrict__ list, const int* __restrict__ count,
                        const float* __restrict__ pv, const int* __restrict__ pi,
                        int* __restrict__ idx)
{
    const int t = blockIdx.x * 256 + threadIdx.x;
    if (t >= *count) return;
    float bv = -3e38f; int bi = 0x7fffffff;
    #pragma unroll
    for (int kc = 0; kc < 8; ++kc) {
        const float v = pv[t * 8 + kc]; const int ii = pi[t * 8 + kc];
        if (v > bv || (v == bv && ii < bi)) { bv = v; bi = ii; }
    }
    idx[list[t]] = bi;
}

// ---------- K3a: counts + idx-as-float output ----------
__global__ void k_counts(const int* __restrict__ idx, float* __restrict__ oCs,
                         float* __restrict__ oIdx)
{
    int n = blockIdx.x * 256 + threadIdx.x;
    if (n >= NROWS) return;
    int k = idx[n];
    oIdx[n] = (float)k;
    atomicAdd(&oCs[k], OMD);
}

// ---------- K3b: embed_avg scatter-add ----------
__global__ __launch_bounds__(256) void k_scatter(const float* __restrict__ z,
                                                 const int* __restrict__ idx,
                                                 float* __restrict__ oAvg)
{
    int tid = threadIdx.x;
    int n0  = blockIdx.x * 64;
    int b   = n0 >> 12, hw0 = n0 & 4095;
    const float* zb = z + (size_t)b * DIM * HW + hw0;
    int r = tid & 63, w = tid >> 6;
    int k = idx[n0 + r];
    float* dst = oAvg + (size_t)k * DIM;
    #pragma unroll 4
    for (int i = 0; i < 64; ++i) {
        int d = i * 4 + w;
        atomicAdd(&dst[d], OMD * zb[(size_t)d * HW + r]);
    }
}

// ---------- K4: z_q gather + straight-through ----------
__global__ void k_zq(const float* __restrict__ z, const float* __restrict__ emb,
                     const int* __restrict__ idx,
                     float* __restrict__ oZqSt, float* __restrict__ oZq)
{
    int t  = blockIdx.x * 256 + threadIdx.x;
    int hw = t & 4095;
    int d  = (t >> 12) & 255;
    int b  = t >> 20;
    int k  = idx[b * HW + hw];
    float e  = emb[(size_t)k * DIM + d];
    float zv = z[t];
    oZq[t]   = e;
    oZqSt[t] = zv + (e - zv);
}

// ---------- K5: n = sum(new_cluster_size) ----------
__global__ __launch_bounds__(256) void k_nsum(const float* __restrict__ oCs,
                                              float* __restrict__ nsum)
{
    __shared__ float red[256];
    float s = 0.0f;
    for (int t = threadIdx.x; t < KCODES; t += 256) s += oCs[t];
    red[threadIdx.x] = s;
    __syncthreads();
    for (int st = 128; st > 0; st >>= 1) {
        if (threadIdx.x < st) red[threadIdx.x] += red[threadIdx.x + st];
        __syncthreads();
    }
    if (threadIdx.x == 0) *nsum = red[0];
}

// ---------- K6: new_embedding = l2norm(new_embed_avg / cs) ----------
__global__ __launch_bounds__(256) void k_final_embed(const float* __restrict__ oAvg,
                                                     const float* __restrict__ oCs,
                                                     const float* __restrict__ nsum,
                                                     float* __restrict__ oEmb)
{
    int gw   = (blockIdx.x * 256 + threadIdx.x) >> 6;
    int lane = threadIdx.x & 63;
    if (gw >= KCODES) return;
    float nt = *nsum;
    float cs = (oCs[gw] + EPSF) / (nt + (float)KCODES * EPSF) * nt;
    float4 v = *(const float4*)(oAvg + (size_t)gw * DIM + lane * 4);
    float t0 = v.x / cs, t1 = v.y / cs, t2 = v.z / cs, t3 = v.w / cs;
    float ss = t0 * t0 + t1 * t1 + t2 * t2 + t3 * t3;
    #pragma unroll
    for (int m = 1; m < 64; m <<= 1) ss += __shfl_xor(ss, m, 64);
    float scale = 1.0f / fmaxf(sqrtf(ss), 1e-12f);
    float4 o = {t0 * scale, t1 * scale, t2 * scale, t3 * scale};
    *(float4*)(oEmb + (size_t)gw * DIM + lane * 4) = o;
}

extern "C" void kernel_launch(void* const* d_in, const int* in_sizes, int n_in,
                              void* d_out, int out_size, void* d_ws, size_t ws_size,
                              hipStream_t stream)
{
    const float* z       = (const float*)d_in[0];
    const float* emb     = (const float*)d_in[1];
    const float* cluster = (const float*)d_in[2];
    const float* eavg    = (const float*)d_in[3];

    float* out   = (float*)d_out;
    float* oZqSt = out;                    // 8388608
    float* oIdx  = out + 8388608;          // 32768
    float* oZq   = out + 8421376;          // 8388608
    float* oEmb  = out + 16809984;         // 2097152
    float* oCs   = out + 18907136;         // 8192
    float* oAvg  = out + 18915328;         // 2097152

    // scratch living in late-written out-regions:
    unsigned short* Ah = (unsigned short*)oZqSt;            // 33.5 MB region
    unsigned short* Al = Ah + 8388608;
    unsigned short* Bh = (unsigned short*)oZq;              // head of oZq region
    unsigned short* Bl = Bh + 2097152;
    float* pv = oZq + 4194304;                              // partials (past Bh/Bl)
    int*   pi = (int*)(oZq + 4194304 + 262144);

    float* ws    = (float*)d_ws;
    float* eT    = ws;                              // 2097152 floats (8 MB)
    float* rnorm = ws + 2097152;                    // 8192
    int*   idx   = (int*)(ws + 2097152 + 8192);     // 32768 ints
    float* nsum  = (float*)(idx + 32768);           // 1
    int*   flags = (int*)(nsum + 1);                // 32768 ints
    int*   list  = flags + 32768;                   // 32768 ints
    int*   count = list + 32768;                    // 1 int

    k_rnorm      <<<2048, 256, 0, stream>>>(emb, rnorm);
    k_transpose  <<<512, 256, 0, stream>>>(emb, rnorm, eT);
    k_split_e    <<<2048, 256, 0, stream>>>(emb, rnorm, Bh, Bl);
    k_split_z    <<<512, 256, 0, stream>>>(z, Ah, Al);
    k_init       <<<8192, 256, 0, stream>>>(eavg, cluster, oAvg, oCs, count);
    k_gemm_bf16  <<<256, 256, 0, stream>>>(Ah, Al, Bh, Bl, idx, flags);
    k_flagscan   <<<128, 256, 0, stream>>>(flags, list, count);
    k_exact2     <<<2048, 256, 0, stream>>>(z, eT, list, count, pv, pi);
    k_merge      <<<128, 256, 0, stream>>>(list, count, pv, pi, idx);
    k_counts     <<<128, 256, 0, stream>>>(idx, oCs, oIdx);
    k_scatter    <<<512, 256, 0, stream>>>(z, idx, oAvg);
    k_zq         <<<32768, 256, 0, stream>>>(z, emb, idx, oZqSt, oZq);
    k_nsum       <<<1, 256, 0, stream>>>(oCs, nsum);
    k_final_embed<<<2048, 256, 0, stream>>>(oAvg, oCs, nsum, oEmb);
}

// Round 6
// 713.463 us; speedup vs baseline: 4.3898x; 2.0855x over previous
//
#include <hip/hip_runtime.h>
#include <hip/hip_bf16.h>
#include <math.h>

#define KCODES 8192
#define DIM 256
#define HW 4096            // H*W
#define NROWS 32768        // B*H*W
#define DECAYF 0.99f
#define OMD 0.01f
#define EPSF 1e-5f
#define MARGIN 2.5e-4f     // rigorous delta <= ~5e-5 (normalized z,e; C-S bound); 2.5x safety

typedef __attribute__((ext_vector_type(8)))  short  short8;
typedef __attribute__((ext_vector_type(16))) float  f32x16;
typedef __attribute__((ext_vector_type(8)))  unsigned short ushort8v;
typedef __attribute__((ext_vector_type(4)))  unsigned short ushort4v;

__device__ inline unsigned short f2bf_rne(float f) {
    unsigned u = __builtin_bit_cast(unsigned, f);
    u += 0x7fffu + ((u >> 16) & 1u);
    return (unsigned short)(u >> 16);
}
__device__ inline float bf2f(unsigned short u) {
    unsigned x = ((unsigned)u) << 16;
    return __builtin_bit_cast(float, x);
}

// swizzle within a 16KB term-buffer: 512B per code-col; spread cols across 16B slots
#define SWZ16K(l) ((l) ^ ((((l) >> 9) & 7) << 4))

// ---------- K1a: inverse L2 norms of embedding rows ----------
__global__ __launch_bounds__(256) void k_rnorm(const float* __restrict__ emb,
                                               float* __restrict__ rnorm)
{
    int gw   = (blockIdx.x * 256 + threadIdx.x) >> 6;
    int lane = threadIdx.x & 63;
    if (gw >= KCODES) return;
    float4 v = *(const float4*)(emb + (size_t)gw * DIM + lane * 4);
    float ss = v.x * v.x + v.y * v.y + v.z * v.z + v.w * v.w;
    #pragma unroll
    for (int m = 1; m < 64; m <<= 1) ss += __shfl_xor(ss, m, 64);
    if (lane == 0) rnorm[gw] = 1.0f / fmaxf(sqrtf(ss), 1e-12f);
}

// ---------- K1b: eT[d][k] fp32 (feeds exact fallback bit-identically) ----------
__global__ __launch_bounds__(256) void k_transpose(const float* __restrict__ emb,
                                                   const float* __restrict__ rnorm,
                                                   float* __restrict__ eT)
{
    __shared__ float tile[64][65];
    int kb = blockIdx.x >> 2;
    int db = blockIdx.x & 3;
    int k0 = kb * 64, d0 = db * 64;
    int lane = threadIdx.x & 63;
    int w    = threadIdx.x >> 6;
    #pragma unroll
    for (int it = 0; it < 16; ++it) {
        int row = it * 4 + w;
        tile[row][lane] = emb[(size_t)(k0 + row) * DIM + d0 + lane] * rnorm[k0 + row];
    }
    __syncthreads();
    #pragma unroll
    for (int it = 0; it < 16; ++it) {
        int drow = it * 4 + w;
        eT[(size_t)(d0 + drow) * KCODES + k0 + lane] = tile[lane][drow];
    }
}

// ---------- K1c: init EMA outputs + zero flag counter ----------
__global__ void k_init(const float* __restrict__ eavg, const float* __restrict__ cs,
                       float* __restrict__ oAvg, float* __restrict__ oCs,
                       int* __restrict__ count)
{
    int t = blockIdx.x * 256 + threadIdx.x;
    if (t == 0 && blockIdx.x == 0) *count = 0;
    if (t < KCODES * DIM) oAvg[t] = DECAYF * eavg[t];
    if (t < KCODES)       oCs[t]  = DECAYF * cs[t];
}

// ---------- split NORMALIZED z into bf16 hi/lo row-major [n][d]; store ||z|| ----------
__global__ __launch_bounds__(256) void k_split_z(const float* __restrict__ z,
                                                 unsigned short* __restrict__ Ah,
                                                 unsigned short* __restrict__ Al,
                                                 float* __restrict__ znorm)
{
    __shared__ float zT[DIM][64];
    __shared__ float part[4][64];
    __shared__ float rnS[64];
    const int tid = threadIdx.x;
    const int n0 = blockIdx.x * 64;
    const int b = n0 >> 12, hw0 = n0 & 4095;
    const float* zb = z + (size_t)b * DIM * HW + hw0;
    const int r = tid & 63, w = tid >> 6;
    #pragma unroll 8
    for (int i = 0; i < 64; ++i) {
        const int d = i * 4 + w;
        zT[d][r] = zb[(size_t)d * HW + r];
    }
    __syncthreads();
    float ss = 0.f;
    #pragma unroll 8
    for (int dd = 0; dd < 64; ++dd) {
        const float v = zT[w * 64 + dd][r];
        ss = fmaf(v, v, ss);
    }
    part[w][r] = ss;
    __syncthreads();
    if (tid < 64) {
        const float s = part[0][tid] + part[1][tid] + part[2][tid] + part[3][tid];
        const float nr = sqrtf(s);
        znorm[n0 + tid] = nr;
        rnS[tid] = 1.0f / fmaxf(nr, 1e-12f);
    }
    __syncthreads();
    const float rn = rnS[r];
    const size_t ob = (size_t)(n0 + r) * DIM + w * 64;
    #pragma unroll
    for (int g = 0; g < 8; ++g) {
        ushort8v hu, lu;
        #pragma unroll
        for (int e = 0; e < 8; ++e) {
            const float f = zT[w * 64 + g * 8 + e][r] * rn;
            const unsigned short h = f2bf_rne(f);
            hu[e] = h;
            lu[e] = f2bf_rne(f - bf2f(h));
        }
        *(ushort8v*)(Ah + ob + g * 8) = hu;
        *(ushort8v*)(Al + ob + g * 8) = lu;
    }
}

// ---------- split normalized codes into bf16 hi/lo, row-major [code][d] ----------
__global__ __launch_bounds__(256) void k_split_e(const float* __restrict__ emb,
                                                 const float* __restrict__ rnorm,
                                                 unsigned short* __restrict__ Bh,
                                                 unsigned short* __restrict__ Bl)
{
    const int gw = (blockIdx.x * 256 + threadIdx.x) >> 6;
    const int lane = threadIdx.x & 63;
    if (gw >= KCODES) return;
    const float sc = rnorm[gw];
    const float4 v = *(const float4*)(emb + (size_t)gw * DIM + lane * 4);
    float f[4] = {v.x * sc, v.y * sc, v.z * sc, v.w * sc};
    ushort4v hu, lu;
    #pragma unroll
    for (int e = 0; e < 4; ++e) {
        const unsigned short h = f2bf_rne(f[e]);
        hu[e] = h;
        lu[e] = f2bf_rne(f[e] - bf2f(h));
    }
    *(ushort4v*)(Bh + (size_t)gw * DIM + lane * 4) = hu;
    *(ushort4v*)(Bl + (size_t)gw * DIM + lane * 4) = lu;
}

// ---------- K2: 32x32x16 MFMA bf16-split GEMM + per-(row,colhalf) top-2 ----------
// 512 blocks: (rowgrp 0..255) x (colgrp 0..1). Block: 128 rows x 4096 cols.
// 4 waves x 32 rows. 32-col chunks, double-buffered 64KB LDS -> 2 blocks/CU.
__global__ __launch_bounds__(256, 2) void k_gemm_bf16(
    const unsigned short* __restrict__ Ah, const unsigned short* __restrict__ Al,
    const unsigned short* __restrict__ Bh, const unsigned short* __restrict__ Bl,
    float* __restrict__ pv1, float* __restrict__ pv2, int* __restrict__ pi1)
{
    __shared__ unsigned short Blds[2][2][8192];       // [buf][hi/lo][16KB]
    const int tid = threadIdx.x;
    const int w = tid >> 6, lane = tid & 63;
    const int c31 = lane & 31, hk = lane >> 5;
    const int rowgrp = blockIdx.x >> 1, colgrp = blockIdx.x & 1;
    const int n0 = rowgrp * 128;
    const int c0 = colgrp * 128;                      // chunk base (global chunk idx)
    const int row = n0 + w * 32 + c31;

    // A fragments: lane holds row=c31(+w*32), k = ks*16 + hk*8 .. +8
    short8 ah[16], al[16];
    {
        const size_t rb = (size_t)row * DIM + hk * 8;
        #pragma unroll
        for (int ks = 0; ks < 16; ++ks) {
            ah[ks] = *(const short8*)(Ah + rb + ks * 16);
            al[ks] = *(const short8*)(Al + rb + ks * 16);
        }
    }

    float b1v[16], b2v[16]; int b1i[16];
    #pragma unroll
    for (int q = 0; q < 16; ++q) { b1v[q] = -3e38f; b2v[q] = -3e38f; b1i[q] = 0; }

    auto stage = [&](int buf, int c) {                // 8 global_load_lds per wave
        #pragma unroll
        for (int term = 0; term < 2; ++term) {
            const unsigned short* src = (term ? Bl : Bh) + (size_t)c * 8192;
            #pragma unroll
            for (int i = 0; i < 4; ++i) {
                const int lbase = w * 4096 + i * 1024;        // wave-uniform
                const int l = lbase + lane * 16;
                const int s = SWZ16K(l) >> 1;                 // ushort offset
                __builtin_amdgcn_global_load_lds(
                    (const __attribute__((address_space(1))) unsigned int*)(src + s),
                    (__attribute__((address_space(3))) unsigned int*)((char*)&Blds[buf][term][0] + lbase),
                    16, 0, 0);
            }
        }
    };

    stage(0, c0);

    const int rb   = c31 * 512 + hk * 16;
    const int sw   = (c31 & 7) << 4;

    for (int cl = 0; cl < 128; ++cl) {
        const int buf = cl & 1;
        const int c = c0 + cl;
        if (cl < 127) {
            stage(buf ^ 1, c + 1);
            asm volatile("s_waitcnt vmcnt(8)" ::: "memory");  // this chunk landed; next in flight
        } else {
            asm volatile("s_waitcnt vmcnt(0)" ::: "memory");
        }
        __builtin_amdgcn_sched_barrier(0);
        __builtin_amdgcn_s_barrier();

        f32x16 acc;
        #pragma unroll
        for (int q = 0; q < 16; ++q) acc[q] = 0.0f;

        const char* pbuf = (const char*)&Blds[buf][0][0];
        #pragma unroll
        for (int ks = 0; ks < 16; ++ks) {
            const int byte = (rb + ks * 32) ^ sw;             // read-side swizzle
            const short8 bh = *(const short8*)(pbuf + byte);
            const short8 bl = *(const short8*)(pbuf + byte + 16384);
            acc = __builtin_amdgcn_mfma_f32_32x32x16_bf16(ah[ks], bh, acc, 0, 0, 0);
            acc = __builtin_amdgcn_mfma_f32_32x32x16_bf16(ah[ks], bl, acc, 0, 0, 0);
            acc = __builtin_amdgcn_mfma_f32_32x32x16_bf16(al[ks], bh, acc, 0, 0, 0);
        }

        const int col = c * 32 + c31;                         // this lane's global col
        #pragma unroll
        for (int q = 0; q < 16; ++q) {
            const float v = acc[q];
            b2v[q] = fmaxf(b2v[q], fminf(b1v[q], v));
            if (v > b1v[q]) { b1i[q] = col; b1v[q] = v; }     // strict > : first occurrence
        }

        __builtin_amdgcn_s_barrier();
    }

    // cross-lane merge within each 32-lane half (cols); tie -> min col
    #pragma unroll
    for (int q = 0; q < 16; ++q) {
        float v1 = b1v[q], v2 = b2v[q]; int i1 = b1i[q];
        #pragma unroll
        for (int m = 1; m < 32; m <<= 1) {
            const float o1 = __shfl_xor(v1, m, 64);
            const int   oi = __shfl_xor(i1, m, 64);
            const float o2 = __shfl_xor(v2, m, 64);
            const float lo = fminf(v1, o1);
            v2 = fmaxf(fmaxf(v2, o2), lo);
            const bool take = (o1 > v1) || (o1 == v1 && oi < i1);
            v1 = take ? o1 : v1;
            i1 = take ? oi : i1;
        }
        if (c31 == 0) {
            // C/D layout (m74/m101): col=lane&31, row=(reg&3)+8*(reg>>2)+4*(lane>>5)
            const int rowl = (q & 3) + 8 * (q >> 2) + 4 * hk;
            const int g = (n0 + w * 32 + rowl) * 2 + colgrp;
            pv1[g] = v1; pv2[g] = v2; pi1[g] = i1;
        }
    }
}

// ---------- merge the two col-half partials per row; emit idx + margin flag ----------
__global__ void k_gmerge(const float* __restrict__ pv1, const float* __restrict__ pv2,
                         const int* __restrict__ pi1,
                         int* __restrict__ idx, int* __restrict__ flags)
{
    const int n = blockIdx.x * 256 + threadIdx.x;
    if (n >= NROWS) return;
    const float va = pv1[2 * n], vb = pv1[2 * n + 1];
    const int   ia = pi1[2 * n], ib = pi1[2 * n + 1];
    const float sa = pv2[2 * n], sb = pv2[2 * n + 1];
    const bool tb = (vb > va) || (vb == va && ib < ia);
    const float v1 = tb ? vb : va;
    const int   i1 = tb ? ib : ia;
    const float v2 = fmaxf(fmaxf(sa, sb), fminf(va, vb));
    idx[n] = i1;
    flags[n] = (v1 - v2 < MARGIN) ? 1 : 0;
}

// ---------- compact flagged rows ----------
__global__ void k_flagscan(const int* __restrict__ flags, int* __restrict__ list,
                           int* __restrict__ count)
{
    int n = blockIdx.x * 256 + threadIdx.x;
    if (n < NROWS && flags[n]) {
        int p = atomicAdd(count, 1);
        list[p] = n;
    }
}

// ---------- batched exact recheck (raw z, round-3-proven fp32 chain) ----------
__global__ __launch_bounds__(256) void k_exact2(const float* __restrict__ z,
                                                const float* __restrict__ eT,
                                                const int* __restrict__ list,
                                                const int* __restrict__ count,
                                                float* __restrict__ pv,
                                                int* __restrict__ pi)
{
    __shared__ float zl[16][256];
    __shared__ float sv[256];
    __shared__ int   si[256];
    const int cnt = *count;
    const int totalJobs = ((cnt + 15) >> 4) << 3;
    const int t = threadIdx.x;

    for (int j = blockIdx.x; j < totalJobs; j += gridDim.x) {
        const int slot = j >> 3, kc = j & 7;
        __syncthreads();
        #pragma unroll
        for (int i = 0; i < 16; ++i) {
            const int s = slot * 16 + i;
            const int n = (s < cnt) ? list[s] : list[0];
            const int b = n >> 12, hw = n & 4095;
            zl[i][t] = z[(size_t)b * DIM * HW + (size_t)t * HW + hw];
        }
        __syncthreads();

        float acc[16][4];
        #pragma unroll
        for (int i = 0; i < 16; ++i)
            #pragma unroll
            for (int q = 0; q < 4; ++q) acc[i][q] = 0.f;

        const float* eb = eT + kc * 1024 + t;
        #pragma unroll 2
        for (int d = 0; d < DIM; ++d) {
            float ev[4];
            #pragma unroll
            for (int q = 0; q < 4; ++q) ev[q] = eb[(size_t)d * KCODES + q * 256];
            #pragma unroll
            for (int i = 0; i < 16; ++i) {
                const float zv = zl[i][d];
                #pragma unroll
                for (int q = 0; q < 4; ++q)
                    acc[i][q] = fmaf(zv, ev[q], acc[i][q]);
            }
        }

        for (int i = 0; i < 16; ++i) {
            float bv = -3e38f; int bi = 0x7fffffff;
            #pragma unroll
            for (int q = 0; q < 4; ++q) {
                const int code = kc * 1024 + t + q * 256;
                const float v = acc[i][q];
                if (v > bv || (v == bv && code < bi)) { bv = v; bi = code; }
            }
            __syncthreads();
            sv[t] = bv; si[t] = bi;
            __syncthreads();
            for (int st = 128; st > 0; st >>= 1) {
                if (t < st) {
                    const float ov = sv[t + st]; const int oi = si[t + st];
                    if (ov > sv[t] || (ov == sv[t] && oi < si[t])) { sv[t] = ov; si[t] = oi; }
                }
                __syncthreads();
            }
            const int s = slot * 16 + i;
            if (t == 0 && s < cnt) {
                pv[s * 8 + kc] = sv[0];
                pi[s * 8 + kc] = si[0];
            }
        }
    }
}

// ---------- merge 8 chunk-partials per flagged row ----------
__global__ void k_merge(const int* __restrict__ list, const int* __restrict__ count,
                        const float* __restrict__ pv, const int* __restrict__ pi,
                        int* __restrict__ idx)
{
    const int t = blockIdx.x * 256 + threadIdx.x;
    if (t >= *count) return;
    float bv = -3e38f; int bi = 0x7fffffff;
    #pragma unroll
    for (int kc = 0; kc < 8; ++kc) {
        const float v = pv[t * 8 + kc]; const int ii = pi[t * 8 + kc];
        if (v > bv || (v == bv && ii < bi)) { bv = v; bi = ii; }
    }
    idx[list[t]] = bi;
}

// ---------- K3a: counts + idx-as-float output ----------
__global__ void k_counts(const int* __restrict__ idx, float* __restrict__ oCs,
                         float* __restrict__ oIdx)
{
    int n = blockIdx.x * 256 + threadIdx.x;
    if (n >= NROWS) return;
    int k = idx[n];
    oIdx[n] = (float)k;
    atomicAdd(&oCs[k], OMD);
}

// ---------- K3b: embed_avg scatter-add, coalesced per-row (d-consecutive lanes) ----------
__global__ __launch_bounds__(256) void k_scatter(const unsigned short* __restrict__ Ah,
                                                 const unsigned short* __restrict__ Al,
                                                 const float* __restrict__ znorm,
                                                 const int* __restrict__ idx,
                                                 float* __restrict__ oAvg)
{
    const int tid = threadIdx.x;
    const int n0 = blockIdx.x * 64;
    const int w = tid >> 6, lane = tid & 63;
    for (int rr = 0; rr < 16; ++rr) {
        const int row = n0 + w * 16 + rr;
        const int k = idx[row];                       // wave-uniform
        const float sc = znorm[row] * OMD;            // z = (h+l)*||z||; fold 0.01
        float* dst = oAvg + (size_t)k * DIM;
        const size_t rb = (size_t)row * DIM;
        #pragma unroll
        for (int j = 0; j < 4; ++j) {
            const int d = j * 64 + lane;              // 64 consecutive floats per instr
            const float v = (bf2f(Ah[rb + d]) + bf2f(Al[rb + d])) * sc;
            atomicAdd(&dst[d], v);
        }
    }
}

// ---------- K4: z_q gather + straight-through ----------
__global__ void k_zq(const float* __restrict__ z, const float* __restrict__ emb,
                     const int* __restrict__ idx,
                     float* __restrict__ oZqSt, float* __restrict__ oZq)
{
    int t  = blockIdx.x * 256 + threadIdx.x;
    int hw = t & 4095;
    int d  = (t >> 12) & 255;
    int b  = t >> 20;
    int k  = idx[b * HW + hw];
    float e  = emb[(size_t)k * DIM + d];
    float zv = z[t];
    oZq[t]   = e;
    oZqSt[t] = zv + (e - zv);
}

// ---------- K5: n = sum(new_cluster_size) ----------
__global__ __launch_bounds__(256) void k_nsum(const float* __restrict__ oCs,
                                              float* __restrict__ nsum)
{
    __shared__ float red[256];
    float s = 0.0f;
    for (int t = threadIdx.x; t < KCODES; t += 256) s += oCs[t];
    red[threadIdx.x] = s;
    __syncthreads();
    for (int st = 128; st > 0; st >>= 1) {
        if (threadIdx.x < st) red[threadIdx.x] += red[threadIdx.x + st];
        __syncthreads();
    }
    if (threadIdx.x == 0) *nsum = red[0];
}

// ---------- K6: new_embedding = l2norm(new_embed_avg / cs) ----------
__global__ __launch_bounds__(256) void k_final_embed(const float* __restrict__ oAvg,
                                                     const float* __restrict__ oCs,
                                                     const float* __restrict__ nsum,
                                                     float* __restrict__ oEmb)
{
    int gw   = (blockIdx.x * 256 + threadIdx.x) >> 6;
    int lane = threadIdx.x & 63;
    if (gw >= KCODES) return;
    float nt = *nsum;
    float cs = (oCs[gw] + EPSF) / (nt + (float)KCODES * EPSF) * nt;
    float4 v = *(const float4*)(oAvg + (size_t)gw * DIM + lane * 4);
    float t0 = v.x / cs, t1 = v.y / cs, t2 = v.z / cs, t3 = v.w / cs;
    float ss = t0 * t0 + t1 * t1 + t2 * t2 + t3 * t3;
    #pragma unroll
    for (int m = 1; m < 64; m <<= 1) ss += __shfl_xor(ss, m, 64);
    float scale = 1.0f / fmaxf(sqrtf(ss), 1e-12f);
    float4 o = {t0 * scale, t1 * scale, t2 * scale, t3 * scale};
    *(float4*)(oEmb + (size_t)gw * DIM + lane * 4) = o;
}

extern "C" void kernel_launch(void* const* d_in, const int* in_sizes, int n_in,
                              void* d_out, int out_size, void* d_ws, size_t ws_size,
                              hipStream_t stream)
{
    const float* z       = (const float*)d_in[0];
    const float* emb     = (const float*)d_in[1];
    const float* cluster = (const float*)d_in[2];
    const float* eavg    = (const float*)d_in[3];

    float* out   = (float*)d_out;
    float* oZqSt = out;                    // 8388608
    float* oIdx  = out + 8388608;          // 32768
    float* oZq   = out + 8421376;          // 8388608
    float* oEmb  = out + 16809984;         // 2097152
    float* oCs   = out + 18907136;         // 8192
    float* oAvg  = out + 18915328;         // 2097152

    // scratch in out-regions written only at the very end:
    unsigned short* Ah = (unsigned short*)oZqSt;            // fills oZqSt region exactly
    unsigned short* Al = Ah + 8388608;
    unsigned short* Bh = (unsigned short*)oZq;              // head of oZq region
    unsigned short* Bl = Bh + 2097152;
    float* pv  = oZq + 4194304;                             // exact2 partials
    int*   pi  = (int*)(oZq + 4194304 + 262144);
    float* pv1 = oZq + 4718592;                             // gemm col-half partials (65536)
    float* pv2 = pv1 + 65536;
    int*   pi1 = (int*)(pv2 + 65536);

    float* ws    = (float*)d_ws;
    float* eT    = ws;                              // 2097152 floats (8 MB)
    float* rnorm = ws + 2097152;                    // 8192
    int*   idx   = (int*)(ws + 2097152 + 8192);     // 32768 ints
    float* nsum  = (float*)(idx + 32768);           // 1
    int*   flags = (int*)(nsum + 1);                // 32768 ints
    int*   list  = flags + 32768;                   // 32768 ints
    int*   count = list + 32768;                    // 1 int
    float* znorm = (float*)(count + 1);             // 32768 floats

    k_rnorm      <<<2048, 256, 0, stream>>>(emb, rnorm);
    k_transpose  <<<512, 256, 0, stream>>>(emb, rnorm, eT);
    k_split_e    <<<2048, 256, 0, stream>>>(emb, rnorm, Bh, Bl);
    k_split_z    <<<512, 256, 0, stream>>>(z, Ah, Al, znorm);
    k_init       <<<8192, 256, 0, stream>>>(eavg, cluster, oAvg, oCs, count);
    k_gemm_bf16  <<<512, 256, 0, stream>>>(Ah, Al, Bh, Bl, pv1, pv2, pi1);
    k_gmerge     <<<128, 256, 0, stream>>>(pv1, pv2, pi1, idx, flags);
    k_flagscan   <<<128, 256, 0, stream>>>(flags, list, count);
    k_exact2     <<<2048, 256, 0, stream>>>(z, eT, list, count, pv, pi);
    k_merge      <<<128, 256, 0, stream>>>(list, count, pv, pi, idx);
    k_counts     <<<128, 256, 0, stream>>>(idx, oCs, oIdx);
    k_scatter    <<<512, 256, 0, stream>>>(Ah, Al, znorm, idx, oAvg);
    k_zq         <<<32768, 256, 0, stream>>>(z, emb, idx, oZqSt, oZq);
    k_nsum       <<<1, 256, 0, stream>>>(oCs, nsum);
    k_final_embed<<<2048, 256, 0, stream>>>(oAvg, oCs, nsum, oEmb);
}